// Round 11
// baseline (482.468 us; speedup 1.0000x reference)
//
#include <hip/hip_runtime.h>
#include <hip/hip_bf16.h>

#define S_LEN 1024
#define BATCH 2048
#define HID   64
#define MB    8               // batch rows per block: TWO chains of 4
#define NBLK  (BATCH / MB)    // 256 blocks -> 1 per CU
#define NTHR  256             // 4 waves; each thread owns (b,u) in BOTH chains

typedef _Float16 half8 __attribute__((ext_vector_type(8)));
typedef float    f32x4 __attribute__((ext_vector_type(4)));

#define L2E 1.4426950408889634f
#define HSTRIDE 80            // 160 B rows: A-frag b128 reads land perfect 2-way (R10: conflicts -98%)

// launch_bounds(256, 1): 1 wave/EU floor -> 512-VGPR budget. Generous on
// purpose: the stationary W_hh fragments must never be rematerialized
// (round-5: 6x regression when the allocator evicted them).
__global__ __launch_bounds__(NTHR, 1) void lstm_kernel(
    const float* __restrict__ x,      // (S, BATCH)
    const float* __restrict__ W_ih,   // (256,1)
    const float* __restrict__ W_hh,   // (256,64)
    const float* __restrict__ b_ih,   // (256,)
    const float* __restrict__ b_hh,   // (256,)
    const float* __restrict__ fc1_w,  // (128,64)
    const float* __restrict__ fc1_b,  // (128,)
    const float* __restrict__ fc2_w,  // (5,128)
    const float* __restrict__ fc2_b,  // (5,)
    float* __restrict__ out)          // (BATCH,5)
{
    // x slice staged ONCE (32 KB): no global loads in the recurrence loop ->
    // the barrier's implicit vmcnt(0) drain is free (R8 win).
    __shared__ __align__(16) float    xs[S_LEN * MB];                  // 32 KB
    __shared__ __align__(16) _Float16 h_buf[2][2][4 * HSTRIDE];        // [chain][parity]
    __shared__ __align__(16) float    head_lds[MB * HID + MB * 128];   // c + fc1

    const int tid  = threadIdx.x;
    const int lane = tid & 63;
    const int wave = tid >> 6;        // 0..3
    const int l15  = lane & 15;
    const int quad = lane >> 4;       // 0..3
    const int b0   = blockIdx.x * MB;

    // ---- stage x: 1024 steps x 8 batches (2048 float4, 8 per thread) ----
    {
        float4* xs4 = (float4*)xs;
        #pragma unroll
        for (int t = 0; t < 8; ++t) {
            const int idx = tid + 256 * t;
            const int s = idx >> 1, half = idx & 1;
            xs4[idx] = *(const float4*)(x + (size_t)s * BATCH + b0 + 4 * half);
        }
    }

    // ---- zero all h buffers (h0 = 0, both chains, both parities) ----
    {
        unsigned* hz = (unsigned*)&h_buf[0][0][0];
        for (int i = tid; i < 2 * 2 * 4 * HSTRIDE / 2; i += NTHR) hz[i] = 0u;
    }

    // ---- stationary W_hh B-fragments, per-wave unit slice (32 VGPRs, SHARED
    // by both chains). wave w, gate g: frag col n=l15 <-> W_hh row g*64+16w+l15.
    // B-frag (16x16x32 f16): lane holds B[k=quad*8+j][n=l15]; k-tile kt adds 32.
    // Pre-scaled by -log2e (sigmoid) / -2log2e (tanh on g gate).
    half8 wfrag[4][2];
    #pragma unroll
    for (int g = 0; g < 4; ++g) {
        const float s = (g == 2) ? (-2.0f * L2E) : (-L2E);
        const float* wr = W_hh + (g * 64 + 16 * wave + l15) * HID + quad * 8;
        #pragma unroll
        for (int kt = 0; kt < 2; ++kt) {
            half8 f;
            #pragma unroll
            for (int j = 0; j < 8; ++j) f[j] = (_Float16)(wr[kt * 32 + j] * s);
            wfrag[g][kt] = f;
        }
    }

    // ---- elementwise ownership: (quad,l15) -> local batch quad, u=16*wave+l15,
    // in chain X (batches b0..b0+3) AND chain Y (batches b0+4..b0+7).
    const int u = 16 * wave + l15;
    float wih_s[4], bias_s[4];
    #pragma unroll
    for (int g = 0; g < 4; ++g) {
        const int n = g * 64 + u;
        const float s = (g == 2) ? (-2.0f * L2E) : (-L2E);
        wih_s[g]  = W_ih[n] * s;
        bias_s[g] = (b_ih[n] + b_hh[n]) * s;
    }

    float cX = 0.0f, cY = 0.0f;
    const f32x4 zero4 = {0.f, 0.f, 0.f, 0.f};

    // hoisted pointers (chain, parity)
    const int aoff = (l15 >> 2) * HSTRIDE + quad * 8;
    const int woff = quad * HSTRIDE + u;
    const _Float16* aX[2] = { &h_buf[0][0][0] + aoff, &h_buf[0][1][0] + aoff };
    const _Float16* aY[2] = { &h_buf[1][0][0] + aoff, &h_buf[1][1][0] + aoff };
    _Float16* wX[2] = { &h_buf[0][0][0] + woff, &h_buf[0][1][0] + woff };
    _Float16* wY[2] = { &h_buf[1][0][0] + woff, &h_buf[1][1][0] + woff };
    const float* xpX = xs + quad;        // step s value at xpX[8*s]
    const float* xpY = xs + 4 + quad;

    __syncthreads();   // x staged + h zeroed visible

    // One chain's full step body (R8-proven math: chained MFMA, plain rcp).
    auto body = [&](float xv, const _Float16* ar, _Float16* hw, float& c) {
        half8 a0 = *(const half8*)(ar);          // k 0..31
        half8 a1 = *(const half8*)(ar + 32);     // k 32..63

        f32x4 acc[4];
        #pragma unroll
        for (int g = 0; g < 4; ++g) {
            acc[g] = __builtin_amdgcn_mfma_f32_16x16x32_f16(a0, wfrag[g][0], zero4, 0, 0, 0);
            acc[g] = __builtin_amdgcn_mfma_f32_16x16x32_f16(a1, wfrag[g][1], acc[g], 0, 0, 0);
        }

        const float gi = acc[0][0] + __builtin_fmaf(xv, wih_s[0], bias_s[0]);
        const float gf = acc[1][0] + __builtin_fmaf(xv, wih_s[1], bias_s[1]);
        const float gg = acc[2][0] + __builtin_fmaf(xv, wih_s[2], bias_s[2]);
        const float go = acc[3][0] + __builtin_fmaf(xv, wih_s[3], bias_s[3]);

        const float i_ = __builtin_amdgcn_rcpf(1.0f + __builtin_amdgcn_exp2f(gi));
        const float f_ = __builtin_amdgcn_rcpf(1.0f + __builtin_amdgcn_exp2f(gf));
        const float g_ = 2.0f * __builtin_amdgcn_rcpf(1.0f + __builtin_amdgcn_exp2f(gg)) - 1.0f;
        const float o_ = __builtin_amdgcn_rcpf(1.0f + __builtin_amdgcn_exp2f(go));

        c = f_ * c + i_ * g_;
        const float th = 2.0f * __builtin_amdgcn_rcpf(
                             1.0f + __builtin_amdgcn_exp2f((-2.0f * L2E) * c)) - 1.0f;
        const float h = o_ * th;
        hw[0] = (_Float16)h;
    };

    for (int s = 0; s < S_LEN; s += 2) {
        // period 1: both chains step s (read parity 0, write parity 1)
        body(xpX[8 * s], aX[0], wX[1], cX);
        body(xpY[8 * s], aY[0], wY[1], cY);
        __syncthreads();
        // period 2: both chains step s+1 (read parity 1, write parity 0)
        body(xpX[8 * (s + 1)], aX[1], wX[0], cX);
        body(xpY[8 * (s + 1)], aY[1], wY[0], cY);
        __syncthreads();
    }

    // ---------- fused FC head on final cell states (no activation) ----------
    float* c_lds  = head_lds;            // MB*64 floats: [b][u]
    float* h1_lds = head_lds + MB * HID; // MB*128 floats: [b][j]
    c_lds[quad * HID + u]       = cX;    // chain X: local batches 0..3
    c_lds[(4 + quad) * HID + u] = cY;    // chain Y: local batches 4..7
    __syncthreads();

    for (int idx = tid; idx < MB * 128; idx += NTHR) {
        const int b = idx >> 7, j = idx & 127;
        const float* wrow = fc1_w + j * HID;
        const float* crow = c_lds + b * HID;
        float acc = fc1_b[j];
        #pragma unroll
        for (int k = 0; k < HID; k += 4)
            acc += crow[k] * wrow[k] + crow[k+1] * wrow[k+1]
                 + crow[k+2] * wrow[k+2] + crow[k+3] * wrow[k+3];
        h1_lds[idx] = acc;
    }
    __syncthreads();

    if (tid < MB * 5) {
        const int b = tid / 5, q = tid % 5;
        const float* wrow = fc2_w + q * 128;
        const float* hrow = h1_lds + b * 128;
        float acc = fc2_b[q];
        #pragma unroll 4
        for (int j = 0; j < 128; ++j) acc += hrow[j] * wrow[j];
        out[(b0 + b) * 5 + q] = acc;
    }
}

extern "C" void kernel_launch(void* const* d_in, const int* in_sizes, int n_in,
                              void* d_out, int out_size, void* d_ws, size_t ws_size,
                              hipStream_t stream) {
    const float* x     = (const float*)d_in[0];
    const float* W_ih  = (const float*)d_in[1];
    const float* W_hh  = (const float*)d_in[2];
    const float* b_ih  = (const float*)d_in[3];
    const float* b_hh  = (const float*)d_in[4];
    const float* fc1_w = (const float*)d_in[5];
    const float* fc1_b = (const float*)d_in[6];
    const float* fc2_w = (const float*)d_in[7];
    const float* fc2_b = (const float*)d_in[8];
    float* out = (float*)d_out;

    lstm_kernel<<<NBLK, NTHR, 0, stream>>>(x, W_ih, W_hh, b_ih, b_hh,
                                           fc1_w, fc1_b, fc2_w, fc2_b, out);
}

// Round 12
// 389.936 us; speedup vs baseline: 1.2373x; 1.2373x over previous
//
#include <hip/hip_runtime.h>
#include <hip/hip_bf16.h>

#define S_LEN 1024
#define BATCH 2048
#define HID   64
#define MB    8               // batch rows per block
#define NBLK  (BATCH / MB)    // 256 blocks -> exactly 1 per CU
#define NTHR  512             // 8 waves = 2 per SIMD (full pair occupancy)

typedef _Float16 half8 __attribute__((ext_vector_type(8)));
typedef float    f32x4 __attribute__((ext_vector_type(4)));

#define L2E 1.4426950408889634f
#define HSTRIDE 80            // 160 B rows: A-frag b128 reads land 2-way (free)

// launch_bounds(512, 2): 2 waves/EU -> 256-VGPR budget. min-waves arg is
// LOAD-BEARING: without it the allocator evicts the stationary W_hh fragments
// and rematerializes them per step (round-5: 6x regression).
__global__ __launch_bounds__(NTHR, 2) void lstm_kernel(
    const float* __restrict__ x,      // (S, BATCH)
    const float* __restrict__ W_ih,   // (256,1)
    const float* __restrict__ W_hh,   // (256,64)
    const float* __restrict__ b_ih,   // (256,)
    const float* __restrict__ b_hh,   // (256,)
    const float* __restrict__ fc1_w,  // (128,64)
    const float* __restrict__ fc1_b,  // (128,)
    const float* __restrict__ fc2_w,  // (5,128)
    const float* __restrict__ fc2_b,  // (5,)
    float* __restrict__ out)          // (BATCH,5)
{
    // x slice staged ONCE (32 KB): no global loads in the loop -> barrier's
    // implicit vmcnt(0) drain is free (R8 win).
    __shared__ __align__(16) float    xs[S_LEN * MB];                // 32 KB
    __shared__ __align__(16) _Float16 h_buf[2][MB * HSTRIDE];        // 2x1280 B
    __shared__ __align__(16) float    head_lds[MB * HID + MB * 128]; // c + fc1

    const int tid  = threadIdx.x;
    const int lane = tid & 63;
    const int wave = tid >> 6;        // 0..7
    const int ws   = wave & 3;        // unit-slice index
    const int bh   = wave >> 2;       // batch-half index
    const int l15  = lane & 15;
    const int quad = lane >> 4;       // 0..3
    const int b0   = blockIdx.x * MB;

    // ---- stage x: 1024 steps x 8 batches = 2048 float4, 4 per thread ----
    {
        float4* xs4 = (float4*)xs;
        #pragma unroll
        for (int t = 0; t < 4; ++t) {
            const int idx = tid + 512 * t;
            const int s = idx >> 1, half = idx & 1;
            xs4[idx] = *(const float4*)(x + (size_t)s * BATCH + b0 + 4 * half);
        }
    }

    // ---- zero both h buffers (h0 = 0) ----
    {
        unsigned* hz = (unsigned*)&h_buf[0][0];
        for (int i = tid; i < 2 * MB * HSTRIDE / 2; i += NTHR) hz[i] = 0u;
    }

    // ---- stationary W_hh B-fragments, per-unit-slice (32 VGPRs) ----
    // slice ws, gate g: frag col n=l15 <-> W_hh row g*64 + 16*ws + l15.
    // B-frag (16x16x32 f16): lane holds B[k=quad*8+j][n=l15]; k-tile kt adds 32.
    // Pre-scaled by -log2e (sigmoid) / -2log2e (tanh on g gate).
    half8 wfrag[4][2];
    #pragma unroll
    for (int g = 0; g < 4; ++g) {
        const float s = (g == 2) ? (-2.0f * L2E) : (-L2E);
        const float* wr = W_hh + (g * 64 + 16 * ws + l15) * HID + quad * 8;
        #pragma unroll
        for (int kt = 0; kt < 2; ++kt) {
            half8 f;
            #pragma unroll
            for (int j = 0; j < 8; ++j) f[j] = (_Float16)(wr[kt * 32 + j] * s);
            wfrag[g][kt] = f;
        }
    }

    // ---- elementwise ownership: thread -> b = 2*quad + bh, u = 16*ws + l15 ----
    const int bb = 2 * quad + bh;
    const int u  = 16 * ws + l15;
    float wih_s[4], bias_s[4];
    #pragma unroll
    for (int g = 0; g < 4; ++g) {
        const int n = g * 64 + u;
        const float s = (g == 2) ? (-2.0f * L2E) : (-L2E);
        wih_s[g]  = W_ih[n] * s;
        bias_s[g] = (b_ih[n] + b_hh[n]) * s;
    }

    float c = 0.0f;
    const f32x4 zero4 = {0.f, 0.f, 0.f, 0.f};   // persistent C-operand regs

    // hoisted pointers. A-replication x2: A[m][k] = h[m>>1][k]
    // => C[row=quad*4+r][col=l15] = gates[batch=row>>1][unit]; this thread's
    // batch bb=2*quad+bh sits at r = 2*bh (rows 2bh, 2bh+1 duplicate).
    const int aoff = (l15 >> 1) * HSTRIDE + quad * 8;
    const _Float16* a0p = &h_buf[0][0] + aoff;
    const _Float16* a1p = &h_buf[1][0] + aoff;
    _Float16* w0p = &h_buf[0][0] + bb * HSTRIDE + u;
    _Float16* w1p = &h_buf[1][0] + bb * HSTRIDE + u;
    const float* xp = xs + bb;                   // step s value at xp[8*s]
    const bool hi = (bh != 0);                   // wave-uniform reg-select

    __syncthreads();   // x staged + h zeroed visible

    auto body = [&](int s, const _Float16* ar, _Float16* hw) {
        const float xv = xp[8 * s];              // ds broadcast (8 lanes/addr)

        half8 a0 = *(const half8*)(ar);          // k 0..31
        half8 a1 = *(const half8*)(ar + 32);     // k 32..63

        f32x4 acc[4];
        #pragma unroll
        for (int g = 0; g < 4; ++g) {
            acc[g] = __builtin_amdgcn_mfma_f32_16x16x32_f16(a0, wfrag[g][0], zero4, 0, 0, 0);
            acc[g] = __builtin_amdgcn_mfma_f32_16x16x32_f16(a1, wfrag[g][1], acc[g], 0, 0, 0);
        }

        // gate g for this thread = acc[g][2*bh] (4 wave-uniform cndmasks)
        const float gi = (hi ? acc[0][2] : acc[0][0]) + __builtin_fmaf(xv, wih_s[0], bias_s[0]);
        const float gf = (hi ? acc[1][2] : acc[1][0]) + __builtin_fmaf(xv, wih_s[1], bias_s[1]);
        const float gg = (hi ? acc[2][2] : acc[2][0]) + __builtin_fmaf(xv, wih_s[2], bias_s[2]);
        const float go = (hi ? acc[3][2] : acc[3][0]) + __builtin_fmaf(xv, wih_s[3], bias_s[3]);

        const float i_ = __builtin_amdgcn_rcpf(1.0f + __builtin_amdgcn_exp2f(gi));
        const float f_ = __builtin_amdgcn_rcpf(1.0f + __builtin_amdgcn_exp2f(gf));
        const float g_ = 2.0f * __builtin_amdgcn_rcpf(1.0f + __builtin_amdgcn_exp2f(gg)) - 1.0f;
        const float o_ = __builtin_amdgcn_rcpf(1.0f + __builtin_amdgcn_exp2f(go));

        c = f_ * c + i_ * g_;
        const float th = 2.0f * __builtin_amdgcn_rcpf(
                             1.0f + __builtin_amdgcn_exp2f((-2.0f * L2E) * c)) - 1.0f;
        const float h = o_ * th;

        hw[0] = (_Float16)h;
        __syncthreads();   // ONE 8-wave barrier per step; no vm ops in flight
    };

    for (int s = 0; s < S_LEN; s += 2) {
        body(s,     a0p, w1p);   // read h_buf[0], write h_buf[1]
        body(s + 1, a1p, w0p);   // read h_buf[1], write h_buf[0]
    }

    // ---------- fused FC head on final cell state (no activation) ----------
    float* c_lds  = head_lds;            // MB*64 floats: [b][u]
    float* h1_lds = head_lds + MB * HID; // MB*128 floats: [b][j]
    c_lds[bb * HID + u] = c;
    __syncthreads();

    for (int idx = tid; idx < MB * 128; idx += NTHR) {
        const int b = idx >> 7, j = idx & 127;
        const float* wrow = fc1_w + j * HID;
        const float* crow = c_lds + b * HID;
        float acc = fc1_b[j];
        #pragma unroll
        for (int k = 0; k < HID; k += 4)
            acc += crow[k] * wrow[k] + crow[k+1] * wrow[k+1]
                 + crow[k+2] * wrow[k+2] + crow[k+3] * wrow[k+3];
        h1_lds[idx] = acc;
    }
    __syncthreads();

    if (tid < MB * 5) {
        const int b = tid / 5, q = tid % 5;
        const float* wrow = fc2_w + q * 128;
        const float* hrow = h1_lds + b * 128;
        float acc = fc2_b[q];
        #pragma unroll 4
        for (int j = 0; j < 128; ++j) acc += hrow[j] * wrow[j];
        out[(b0 + b) * 5 + q] = acc;
    }
}

extern "C" void kernel_launch(void* const* d_in, const int* in_sizes, int n_in,
                              void* d_out, int out_size, void* d_ws, size_t ws_size,
                              hipStream_t stream) {
    const float* x     = (const float*)d_in[0];
    const float* W_ih  = (const float*)d_in[1];
    const float* W_hh  = (const float*)d_in[2];
    const float* b_ih  = (const float*)d_in[3];
    const float* b_hh  = (const float*)d_in[4];
    const float* fc1_w = (const float*)d_in[5];
    const float* fc1_b = (const float*)d_in[6];
    const float* fc2_w = (const float*)d_in[7];
    const float* fc2_b = (const float*)d_in[8];
    float* out = (float*)d_out;

    lstm_kernel<<<NBLK, NTHR, 0, stream>>>(x, W_ih, W_hh, b_ih, b_hh,
                                           fc1_w, fc1_b, fc2_w, fc2_b, out);
}

// Round 13
// 333.042 us; speedup vs baseline: 1.4487x; 1.1708x over previous
//
#include <hip/hip_runtime.h>
#include <hip/hip_bf16.h>

#define S_LEN 1024
#define BATCH 2048
#define HID   64
#define MB    4               // batch rows per block
#define NBLK  (BATCH / MB)    // 512 blocks -> 2 per CU (measured optimum, R8)
#define NTHR  (MB * HID)      // 256 threads = 4 waves

typedef _Float16 half8 __attribute__((ext_vector_type(8)));
typedef float    f32x4 __attribute__((ext_vector_type(4)));

#define L2E 1.4426950408889634f
#define HSTRIDE 80            // 160 B rows: A-frag b128 reads land 2-way/free
                              // (R10/R12: conflicts 4.28e6 -> 8.6e4 cycles)

// launch_bounds(256, 2): 2 waves/EU = 8 waves/CU = 2 blocks/CU (matches grid).
// min-waves arg is LOAD-BEARING: without it the allocator evicts the stationary
// W_hh fragments and rematerializes them per step (round-5: 6x regression).
__global__ __launch_bounds__(NTHR, 2) void lstm_kernel(
    const float* __restrict__ x,      // (S, BATCH)
    const float* __restrict__ W_ih,   // (256,1)
    const float* __restrict__ W_hh,   // (256,64)
    const float* __restrict__ b_ih,   // (256,)
    const float* __restrict__ b_hh,   // (256,)
    const float* __restrict__ fc1_w,  // (128,64)
    const float* __restrict__ fc1_b,  // (128,)
    const float* __restrict__ fc2_w,  // (5,128)
    const float* __restrict__ fc2_b,  // (5,)
    float* __restrict__ out)          // (BATCH,5)
{
    // x slice staged ONCE (16 KB): no global loads in the recurrence loop ->
    // the barrier's implicit vmcnt(0) drain is free (R8 win).
    __shared__ __align__(16) float    xs[S_LEN * MB];                // 16 KB
    __shared__ __align__(16) _Float16 h_buf[2][MB * HSTRIDE];        // 1280 B
    __shared__ __align__(16) float    head_lds[MB * HID + MB * 128]; // c + fc1

    const int tid  = threadIdx.x;
    const int lane = tid & 63;
    const int wave = tid >> 6;        // 0..3
    const int l15  = lane & 15;
    const int quad = lane >> 4;       // 0..3
    const int b0   = blockIdx.x * MB;

    // ---- stage x: 1024 rows of float4 (x[s][b0..b0+3]), 4 rows/thread ----
    {
        float4* xs4 = (float4*)xs;
        #pragma unroll
        for (int t = 0; t < 4; ++t) {
            const int s = tid + 256 * t;
            xs4[s] = *(const float4*)(x + (size_t)s * BATCH + b0);
        }
    }

    // ---- zero both h buffers (h0 = 0) ----
    {
        unsigned* hz = (unsigned*)&h_buf[0][0];
        for (int i = tid; i < 2 * MB * HSTRIDE / 2; i += NTHR) hz[i] = 0u;
    }

    // ---- stationary W_hh B-fragments, per-wave unit slice (32 VGPRs) ----
    // wave w, gate g: frag col n=l15 <-> W_hh row g*64 + 16w + l15.
    // B-frag (16x16x32 f16): lane holds B[k=quad*8+j][n=l15]; k-tile kt adds 32.
    // Pre-scaled by -log2e (sigmoid) / -2log2e (tanh on g gate).
    half8 wfrag[4][2];
    #pragma unroll
    for (int g = 0; g < 4; ++g) {
        const float s = (g == 2) ? (-2.0f * L2E) : (-L2E);
        const float* wr = W_hh + (g * 64 + 16 * wave + l15) * HID + quad * 8;
        #pragma unroll
        for (int kt = 0; kt < 2; ++kt) {
            half8 f;
            #pragma unroll
            for (int j = 0; j < 8; ++j) f[j] = (_Float16)(wr[kt * 32 + j] * s);
            wfrag[g][kt] = f;
        }
    }

    // ---- elementwise ownership: thread (quad,l15) -> b=quad, u=16*wave+l15 ----
    const int u = 16 * wave + l15;
    float wih_s[4], bias_s[4];
    #pragma unroll
    for (int g = 0; g < 4; ++g) {
        const int n = g * 64 + u;
        const float s = (g == 2) ? (-2.0f * L2E) : (-L2E);
        wih_s[g]  = W_ih[n] * s;
        bias_s[g] = (b_ih[n] + b_hh[n]) * s;
    }

    float c = 0.0f;
    const f32x4 zero4 = {0.f, 0.f, 0.f, 0.f};   // persistent C-operand regs

    // hoisted pointers
    const _Float16* a0p = &h_buf[0][0] + (l15 >> 2) * HSTRIDE + quad * 8;
    const _Float16* a1p = &h_buf[1][0] + (l15 >> 2) * HSTRIDE + quad * 8;
    _Float16* w0p = &h_buf[0][0] + quad * HSTRIDE + u;
    _Float16* w1p = &h_buf[1][0] + quad * HSTRIDE + u;
    const float* xp = xs + quad;                 // step s value at xp[4*s]

    __syncthreads();   // x staged + h zeroed visible

    auto body = [&](int s, const _Float16* ar, _Float16* hw) {
        const float xv = xp[4 * s];              // ds broadcast (16 lanes/addr)

        // ---- MFMA with replicated A: A[m][k] = h[m>>2][k] ----
        // C[row=quad*4+r][col=l15] = gates[batch=quad][unit], identical over r.
        half8 a0 = *(const half8*)(ar);          // k 0..31
        half8 a1 = *(const half8*)(ar + 32);     // k 32..63

        f32x4 acc[4];
        #pragma unroll
        for (int g = 0; g < 4; ++g) {
            acc[g] = __builtin_amdgcn_mfma_f32_16x16x32_f16(a0, wfrag[g][0], zero4, 0, 0, 0);
            acc[g] = __builtin_amdgcn_mfma_f32_16x16x32_f16(a1, wfrag[g][1], acc[g], 0, 0, 0);
        }

        // ---- elementwise: gates register-resident in acc[g][0] ----
        const float gi = acc[0][0] + __builtin_fmaf(xv, wih_s[0], bias_s[0]);
        const float gf = acc[1][0] + __builtin_fmaf(xv, wih_s[1], bias_s[1]);
        const float gg = acc[2][0] + __builtin_fmaf(xv, wih_s[2], bias_s[2]);
        const float go = acc[3][0] + __builtin_fmaf(xv, wih_s[3], bias_s[3]);

        const float i_ = __builtin_amdgcn_rcpf(1.0f + __builtin_amdgcn_exp2f(gi));
        const float f_ = __builtin_amdgcn_rcpf(1.0f + __builtin_amdgcn_exp2f(gf));
        const float g_ = 2.0f * __builtin_amdgcn_rcpf(1.0f + __builtin_amdgcn_exp2f(gg)) - 1.0f;
        const float o_ = __builtin_amdgcn_rcpf(1.0f + __builtin_amdgcn_exp2f(go));

        c = f_ * c + i_ * g_;
        const float th = 2.0f * __builtin_amdgcn_rcpf(
                             1.0f + __builtin_amdgcn_exp2f((-2.0f * L2E) * c)) - 1.0f;
        const float h = o_ * th;

        hw[0] = (_Float16)h;
        __syncthreads();   // only lgkm pressure: no vm ops in flight
    };

    for (int s = 0; s < S_LEN; s += 2) {
        body(s,     a0p, w1p);   // read h_buf[0], write h_buf[1]
        body(s + 1, a1p, w0p);   // read h_buf[1], write h_buf[0]
    }

    // ---------- fused FC head on final cell state (no activation) ----------
    float* c_lds  = head_lds;            // MB*64 floats: [b][u]
    float* h1_lds = head_lds + MB * HID; // MB*128 floats: [b][j]
    c_lds[quad * HID + u] = c;
    __syncthreads();

    for (int idx = tid; idx < MB * 128; idx += NTHR) {
        const int b = idx >> 7, j = idx & 127;
        const float* wrow = fc1_w + j * HID;
        const float* crow = c_lds + b * HID;
        float acc = fc1_b[j];
        #pragma unroll
        for (int k = 0; k < HID; k += 4)
            acc += crow[k] * wrow[k] + crow[k+1] * wrow[k+1]
                 + crow[k+2] * wrow[k+2] + crow[k+3] * wrow[k+3];
        h1_lds[idx] = acc;
    }
    __syncthreads();

    if (tid < MB * 5) {
        const int b = tid / 5, q = tid % 5;
        const float* wrow = fc2_w + q * 128;
        const float* hrow = h1_lds + b * 128;
        float acc = fc2_b[q];
        #pragma unroll 4
        for (int j = 0; j < 128; ++j) acc += hrow[j] * wrow[j];
        out[(b0 + b) * 5 + q] = acc;
    }
}

extern "C" void kernel_launch(void* const* d_in, const int* in_sizes, int n_in,
                              void* d_out, int out_size, void* d_ws, size_t ws_size,
                              hipStream_t stream) {
    const float* x     = (const float*)d_in[0];
    const float* W_ih  = (const float*)d_in[1];
    const float* W_hh  = (const float*)d_in[2];
    const float* b_ih  = (const float*)d_in[3];
    const float* b_hh  = (const float*)d_in[4];
    const float* fc1_w = (const float*)d_in[5];
    const float* fc1_b = (const float*)d_in[6];
    const float* fc2_w = (const float*)d_in[7];
    const float* fc2_b = (const float*)d_in[8];
    float* out = (float*)d_out;

    lstm_kernel<<<NBLK, NTHR, 0, stream>>>(x, W_ih, W_hh, b_ih, b_hh,
                                           fc1_w, fc1_b, fc2_w, fc2_b, out);
}